// Round 1
// baseline (36.833 us; speedup 1.0000x reference)
//
#include <hip/hip_runtime.h>
#include <math.h>

#define B_ 64
#define T_ 64
#define V_ 8192

// log(1e-8), log(1 - 8190e-8)
#define L0_ (-18.420680743952367f)
#define L1_ (-8.190335e-05f)
#define HI_ (0.99991810f)
#define EPS_ (1e-8f)

__device__ __forceinline__ float waveReduceMax(float v) {
    #pragma unroll
    for (int off = 32; off; off >>= 1) v = fmaxf(v, __shfl_xor(v, off));
    return v;
}
__device__ __forceinline__ float waveReduceSum(float v) {
    #pragma unroll
    for (int off = 32; off; off >>= 1) v += __shfl_xor(v, off);
    return v;
}

// One block per row (b*64+t). Computes row max M, softmax denom Z, and l0 (logit of class 0).
// stats[row*4 + {0,1,2}] = M, Z, l0
__global__ __launch_bounds__(256) void k_row_stats(const float* __restrict__ logits,
                                                   float* __restrict__ stats,
                                                   float* __restrict__ out) {
    const int row = blockIdx.x;
    const int tid = threadIdx.x;
    if (row == 0 && tid < 2) out[tid] = 0.0f;  // zero outputs (runs before k_batch in stream order)

    const float4* rp4 = (const float4*)(logits + (size_t)row * V_);
    float4 v[8];
    float lmax = -3.4e38f;
    #pragma unroll
    for (int k = 0; k < 8; ++k) {
        v[k] = rp4[tid + (k << 8)];
        lmax = fmaxf(lmax, fmaxf(fmaxf(v[k].x, v[k].y), fmaxf(v[k].z, v[k].w)));
    }

    const int lane = tid & 63, wid = tid >> 6;
    __shared__ float sredm[4];
    __shared__ float sreds[4];
    float wm = waveReduceMax(lmax);
    if (lane == 0) sredm[wid] = wm;
    __syncthreads();
    const float M = fmaxf(fmaxf(sredm[0], sredm[1]), fmaxf(sredm[2], sredm[3]));

    float lsum = 0.0f;
    #pragma unroll
    for (int k = 0; k < 8; ++k) {
        lsum += __expf(v[k].x - M) + __expf(v[k].y - M) +
                __expf(v[k].z - M) + __expf(v[k].w - M);
    }
    float ws = waveReduceSum(lsum);
    if (lane == 0) sreds[wid] = ws;
    __syncthreads();
    if (tid == 0) {
        float Z = sreds[0] + sreds[1] + sreds[2] + sreds[3];
        stats[row * 4 + 0] = M;
        stats[row * 4 + 1] = Z;
        stats[row * 4 + 2] = v[0].x;  // logits[row][0]
    }
}

// One block per batch b. Gathers G[i][j] = probs[b, headrow_i, headtgt_j],
// reduces col/row maxes -> label terms; computes eos_loss contribution.
__global__ __launch_bounds__(256) void k_batch(const float* __restrict__ logits,
                                               const int* __restrict__ targets,
                                               const float* __restrict__ stats,
                                               float* __restrict__ out) {
    const int b = blockIdx.x;
    const int tid = threadIdx.x;

    __shared__ int   s_row[64];
    __shared__ int   s_tgt[64];
    __shared__ float s_M[64];
    __shared__ float s_iZ[64];
    __shared__ float s_p0[64];
    __shared__ int   s_colmax[64];
    __shared__ int   s_rowmax[64];
    __shared__ int   s_H;

    if (tid < 64) {
        s_colmax[tid] = 0;   // == 0.0f bits; probs are positive so int-compare is monotone
        s_rowmax[tid] = 0;
    }

    // Wave 0: classify rows, compact head list, eos loss.
    if (tid < 64) {
        const int   t  = targets[b * 64 + tid];
        const int   r  = b * 64 + tid;
        const float M  = stats[r * 4 + 0];
        const float Z  = stats[r * 4 + 1];
        const float l0 = stats[r * 4 + 2];
        const float p0 = __expf(l0 - M) / Z;

        const bool head = (t != 0) && (t != 8192);
        const bool isz  = (t == 0);

        unsigned long long hm = __ballot(head);
        int pos = __popcll(hm & ((1ull << tid) - 1ull));
        if (head) {
            s_row[pos] = tid;
            s_tgt[pos] = t;
            s_M[pos]   = M;
            s_iZ[pos]  = 1.0f / Z;
            s_p0[pos]  = p0;
        }
        if (tid == 0) s_H = (int)__popcll(hm);

        // eos loss: rows with t==0 use -log(p0); head rows use -log(1-p0)
        float a  = isz  ? -__logf(p0)        : 0.0f;
        float hh = head ? -__logf(1.0f - p0) : 0.0f;
        float ca = isz  ? 1.0f : 0.0f;
        float ch = head ? 1.0f : 0.0f;
        a  = waveReduceSum(a);
        hh = waveReduceSum(hh);
        ca = waveReduceSum(ca);
        ch = waveReduceSum(ch);
        if (tid == 0) {
            float eos_b = 0.5f * a / (ca + EPS_) + 0.5f * hh / (ch + EPS_);
            atomicAdd(&out[1], eos_b * (1.0f / 64.0f));
        }
    }
    __syncthreads();

    const int H = s_H;
    for (int idx = tid; idx < H * H; idx += 256) {
        const int i = idx / H;           // head-row slot
        const int j = idx - i * H;       // head-target slot
        const float l = logits[((size_t)(b * 64 + s_row[i])) * V_ + s_tgt[j]];
        const float g = __expf(l - s_M[i]) * s_iZ[i];   // probs[b, row_i, tgt_j] > 0
        const int gi = __float_as_int(g);
        atomicMax(&s_colmax[j], gi);
        atomicMax(&s_rowmax[i], gi);
    }
    __syncthreads();

    if (tid < 64) {
        float term = 0.0f;
        if (tid < H) {
            float cm = __int_as_float(s_colmax[tid]);
            cm = fminf(fmaxf(cm, EPS_), HI_);
            const float t1 = -__logf(cm);
            const float rm = __int_as_float(s_rowmax[tid]);
            const float t2 = (-L0_) * (1.0f - s_p0[tid]) - (L1_ - L0_) * rm;
            term = t1 + t2;
        }
        term = waveReduceSum(term);
        if (tid == 0) atomicAdd(&out[0], term);
    }
}

extern "C" void kernel_launch(void* const* d_in, const int* in_sizes, int n_in,
                              void* d_out, int out_size, void* d_ws, size_t ws_size,
                              hipStream_t stream) {
    const float* logits  = (const float*)d_in[0];
    const int*   targets = (const int*)d_in[1];
    float* out   = (float*)d_out;
    float* stats = (float*)d_ws;   // 4096 rows * 4 floats = 64 KiB

    k_row_stats<<<dim3(B_ * T_), dim3(256), 0, stream>>>(logits, stats, out);
    k_batch<<<dim3(B_), dim3(256), 0, stream>>>(logits, targets, stats, out);
}